// Round 1
// baseline (649.579 us; speedup 1.0000x reference)
//
#include <hip/hip_runtime.h>
#include <hip/hip_fp16.h>

#define D_DIM 512
#define BM 128
#define BN 128
#define BK 64

typedef _Float16 h8 __attribute__((ext_vector_type(8)));
typedef _Float16 h4 __attribute__((ext_vector_type(4)));
typedef float f32x4 __attribute__((ext_vector_type(4)));

#define LDS_PTR(p) ((__attribute__((address_space(3))) void*)(p))
#define GLB_PTR(p) ((const __attribute__((address_space(1))) void*)(p))

// ---------------- CSR build ----------------

__global__ void k_zero(int* __restrict__ counts, int n) {
    int i = blockIdx.x * blockDim.x + threadIdx.x;
    if (i < n) counts[i] = 0;
}

__global__ void k_count(const int* __restrict__ row, int* __restrict__ counts, int E) {
    int e = blockIdx.x * blockDim.x + threadIdx.x;
    if (e < E) atomicAdd(&counts[row[e]], 1);
}

__global__ void k_scan_part(const int* __restrict__ counts, int* __restrict__ offsets,
                            int* __restrict__ bsum, int n) {
    __shared__ int s[1024];
    int t = threadIdx.x;
    int i = blockIdx.x * 1024 + t;
    int v = (i < n) ? counts[i] : 0;
    s[t] = v;
    __syncthreads();
    for (int off = 1; off < 1024; off <<= 1) {
        int x = (t >= off) ? s[t - off] : 0;
        __syncthreads();
        s[t] += x;
        __syncthreads();
    }
    if (i < n) offsets[i] = s[t] - v;          // block-local exclusive
    if (t == 1023) bsum[blockIdx.x] = s[t];    // block total
}

__global__ void k_scan_top(int* __restrict__ bsum, int* __restrict__ offsets, int nb, int n) {
    int t = threadIdx.x;  // 64 threads
    int v = (t < nb) ? bsum[t] : 0;
    int orig = v;
    for (int off = 1; off < 64; off <<= 1) {
        int u = __shfl_up(v, off, 64);
        if (t >= off) v += u;
    }
    if (t < nb) bsum[t] = v - orig;            // exclusive block offsets
    if (t == nb - 1) offsets[n] = v;           // grand total = E
}

__global__ void k_scan_add(int* __restrict__ offsets, int* __restrict__ cursor,
                           const int* __restrict__ bsum, int n) {
    int i = blockIdx.x * 1024 + threadIdx.x;
    if (i < n) {
        int o = offsets[i] + bsum[blockIdx.x];
        offsets[i] = o;
        cursor[i] = o;
    }
}

__global__ void k_scatter(const int* __restrict__ row, const int* __restrict__ col,
                          const float* __restrict__ ew, int* __restrict__ cursor,
                          uint2* __restrict__ packed, int E) {
    int e = blockIdx.x * blockDim.x + threadIdx.x;
    if (e < E) {
        int r = row[e];
        int pos = atomicAdd(&cursor[r], 1);
        packed[pos] = make_uint2((unsigned)col[e], __float_as_uint(ew[e]));
    }
}

// ---------------- weight transpose + fp16 convert: wt[n][k] = w[k][n] ----------------

__global__ void k_wt(const float* __restrict__ w, _Float16* __restrict__ wt) {
    __shared__ _Float16 tile[32][33];
    int bx = blockIdx.x & 15, by = blockIdx.x >> 4;
    int tx = threadIdx.x & 31, ty = threadIdx.x >> 5;  // 32 x 8
    for (int r = 0; r < 32; r += 8)
        tile[ty + r][tx] = (_Float16)w[(size_t)(by * 32 + ty + r) * 512 + bx * 32 + tx];
    __syncthreads();
    for (int r = 0; r < 32; r += 8)
        wt[(size_t)(bx * 32 + ty + r) * 512 + by * 32 + tx] = tile[tx][ty + r];
}

// ---------------- GEMM: sup[m][n] (fp16) = X[m][k] * W[k][n] ----------------
// A: reg-staged fp32->f16, XOR-swizzled LDS [m][k]
// B: wt fp16 via global_load_lds(16B), source pre-swizzled so LDS holds swizzled [n][k]
// MFMA 16x16x32 f16: A lane: row=l&15, k=(l>>4)*8+j ; B lane: col=l&15, k=(l>>4)*8+j
// C/D: col=l&15, row=(l>>4)*4+q

__launch_bounds__(256)
__global__ void k_gemm(const float* __restrict__ x, const _Float16* __restrict__ wt,
                       _Float16* __restrict__ sup, int M) {
    __shared__ __align__(16) unsigned char As[BM * BK * 2];  // 16 KB
    __shared__ __align__(16) unsigned char Bs[BN * BK * 2];  // 16 KB

    const int t = threadIdx.x;
    const int lane = t & 63, w = t >> 6;
    const int wr = w >> 1, wc = w & 1;
    const int m0 = blockIdx.x * BM, n0 = blockIdx.y * BN;

    f32x4 acc[4][4] = {};

    const int ar_t = t >> 4;            // row-in-group 0..15
    const int ac_t = (t & 15) * 4;      // f32 col 0,4,..,60
    const int bn_t = t >> 3;            // n within 32-group
    const int bk_sw = ((t & 7) * 16) ^ (((t >> 3) & 7) << 4);  // pre-swizzled src byte off

    for (int kt = 0; kt < D_DIM / BK; ++kt) {
        const int k0 = kt * BK;
        // B: 4x global_load_lds, 16B each, linear LDS dest, swizzled global src
        for (int j = 0; j < 4; ++j) {
            int n = j * 32 + bn_t;
            const char* src = (const char*)(wt + (size_t)(n0 + n) * 512 + k0) + bk_sw;
            __builtin_amdgcn_global_load_lds(GLB_PTR(src), LDS_PTR(Bs + j * 4096 + t * 16),
                                             16, 0, 0);
        }
        // A: reg-staged, 8 issues of float4 -> f16x4, swizzled ds_write
        for (int i = 0; i < 8; ++i) {
            int r = i * 16 + ar_t;
            int g = m0 + r;
            if (g >= M) g = M - 1;
            const float4 v = *(const float4*)(x + (size_t)g * 512 + k0 + ac_t);
            h4 hv;
            hv[0] = (_Float16)v.x; hv[1] = (_Float16)v.y;
            hv[2] = (_Float16)v.z; hv[3] = (_Float16)v.w;
            int addr = r * 128 + ((ac_t * 2) ^ ((r & 7) << 4));
            *(h4*)(As + addr) = hv;
        }
        __syncthreads();

        for (int ks = 0; ks < 2; ++ks) {
            h8 af[4], bf[4];
            const int kb = ks * 64 + ((lane >> 4) * 16);
#pragma unroll
            for (int mb = 0; mb < 4; ++mb) {
                int r = wr * 64 + mb * 16 + (lane & 15);
                af[mb] = *(const h8*)(As + r * 128 + (kb ^ ((r & 7) << 4)));
            }
#pragma unroll
            for (int nb = 0; nb < 4; ++nb) {
                int n = wc * 64 + nb * 16 + (lane & 15);
                bf[nb] = *(const h8*)(Bs + n * 128 + (kb ^ ((n & 7) << 4)));
            }
#pragma unroll
            for (int mb = 0; mb < 4; ++mb)
#pragma unroll
                for (int nb = 0; nb < 4; ++nb)
                    acc[mb][nb] = __builtin_amdgcn_mfma_f32_16x16x32_f16(
                        af[mb], bf[nb], acc[mb][nb], 0, 0, 0);
        }
        __syncthreads();
    }

    const int cr = (lane >> 4) * 4, cc = lane & 15;
#pragma unroll
    for (int mb = 0; mb < 4; ++mb) {
#pragma unroll
        for (int nb = 0; nb < 4; ++nb) {
            int gn = n0 + wc * 64 + nb * 16 + cc;
#pragma unroll
            for (int q = 0; q < 4; ++q) {
                int gm = m0 + wr * 64 + mb * 16 + cr + q;
                if (gm < M)
                    sup[(size_t)gm * 512 + gn] = (_Float16)acc[mb][nb][q];
            }
        }
    }
}

// ---------------- SpMM: one wave per output row ----------------

__global__ void k_spmm(const _Float16* __restrict__ sup, const uint2* __restrict__ packed,
                       const int* __restrict__ offsets, const float* __restrict__ bias,
                       float* __restrict__ out) {
    const int i = blockIdx.x;
    const int l = threadIdx.x;  // 64 lanes, each owns 8 of 512 outputs
    const int s0 = offsets[i], s1 = offsets[i + 1];

    float acc[8];
    const float4 b0 = *(const float4*)(bias + l * 8);
    const float4 b1 = *(const float4*)(bias + l * 8 + 4);
    acc[0] = b0.x; acc[1] = b0.y; acc[2] = b0.z; acc[3] = b0.w;
    acc[4] = b1.x; acc[5] = b1.y; acc[6] = b1.z; acc[7] = b1.w;

    for (int e = s0; e < s1; ++e) {
        uint2 p = packed[e];
        float wgt = __uint_as_float(p.y);
        h8 h = *(const h8*)(sup + (size_t)p.x * 512 + l * 8);
#pragma unroll
        for (int j = 0; j < 8; ++j) acc[j] += wgt * (float)h[j];
    }

    float4 o0 = {acc[0], acc[1], acc[2], acc[3]};
    float4 o1 = {acc[4], acc[5], acc[6], acc[7]};
    *(float4*)(out + (size_t)i * 512 + l * 8) = o0;
    *(float4*)(out + (size_t)i * 512 + l * 8 + 4) = o1;
}

// ---------------- launch ----------------

extern "C" void kernel_launch(void* const* d_in, const int* in_sizes, int n_in,
                              void* d_out, int out_size, void* d_ws, size_t ws_size,
                              hipStream_t stream) {
    const float* x      = (const float*)d_in[0];
    const float* weight = (const float*)d_in[1];
    const float* bias   = (const float*)d_in[2];
    const int*   row    = (const int*)d_in[3];
    const int*   col    = (const int*)d_in[4];
    const float* ew     = (const float*)d_in[5];
    const int M = in_sizes[0] / D_DIM;   // 50000
    const int E = in_sizes[3];           // 1600000
    float* out = (float*)d_out;

    char* ws = (char*)d_ws;
    size_t off = 0;
    auto alloc = [&](size_t bytes) {
        void* p = ws + off;
        off = (off + bytes + 255) & ~(size_t)255;
        return p;
    };
    _Float16* sup  = (_Float16*)alloc((size_t)M * D_DIM * 2);
    _Float16* wt   = (_Float16*)alloc((size_t)512 * 512 * 2);
    int* counts    = (int*)alloc((size_t)M * 4);
    int* offsets   = (int*)alloc((size_t)(M + 1) * 4);
    int* cursor    = (int*)alloc((size_t)M * 4);
    int* bsum      = (int*)alloc(64 * 4);
    uint2* packed  = (uint2*)alloc((size_t)E * 8);
    (void)ws_size; (void)n_in; (void)out_size;

    // CSR build
    k_zero<<<(M + 255) / 256, 256, 0, stream>>>(counts, M);
    k_count<<<(E + 255) / 256, 256, 0, stream>>>(row, counts, E);
    const int SB = (M + 1023) / 1024;  // 49
    k_scan_part<<<SB, 1024, 0, stream>>>(counts, offsets, bsum, M);
    k_scan_top<<<1, 64, 0, stream>>>(bsum, offsets, SB, M);
    k_scan_add<<<SB, 1024, 0, stream>>>(offsets, cursor, bsum, M);
    k_scatter<<<(E + 255) / 256, 256, 0, stream>>>(row, col, ew, cursor, packed, E);

    // dense path
    k_wt<<<256, 256, 0, stream>>>(weight, wt);
    dim3 gg((M + BM - 1) / BM, D_DIM / BN);
    k_gemm<<<gg, 256, 0, stream>>>(x, wt, sup, M);

    // gather-accumulate
    k_spmm<<<M, 64, 0, stream>>>(sup, packed, offsets, bias, out);
}

// Round 2
// 649.132 us; speedup vs baseline: 1.0007x; 1.0007x over previous
//
#include <hip/hip_runtime.h>
#include <hip/hip_fp16.h>

#define D_DIM 512
#define BM 128
#define BN 128
#define BK 64

typedef _Float16 h8 __attribute__((ext_vector_type(8)));
typedef _Float16 h4 __attribute__((ext_vector_type(4)));
typedef float f32x4 __attribute__((ext_vector_type(4)));

#define LDS_PTR(p) ((__attribute__((address_space(3))) void*)(p))
#define GLB_PTR(p) ((const __attribute__((address_space(1))) void*)(p))

// ---------------- CSR build ----------------

__global__ void k_zero(int* __restrict__ counts, int n) {
    int i = blockIdx.x * blockDim.x + threadIdx.x;
    if (i < n) counts[i] = 0;
}

__global__ void k_count(const int* __restrict__ row, int* __restrict__ counts, int E) {
    int e = blockIdx.x * blockDim.x + threadIdx.x;
    if (e < E) atomicAdd(&counts[row[e]], 1);
}

__global__ void k_scan_part(const int* __restrict__ counts, int* __restrict__ offsets,
                            int* __restrict__ bsum, int n) {
    __shared__ int s[1024];
    int t = threadIdx.x;
    int i = blockIdx.x * 1024 + t;
    int v = (i < n) ? counts[i] : 0;
    s[t] = v;
    __syncthreads();
    for (int off = 1; off < 1024; off <<= 1) {
        int x = (t >= off) ? s[t - off] : 0;
        __syncthreads();
        s[t] += x;
        __syncthreads();
    }
    if (i < n) offsets[i] = s[t] - v;          // block-local exclusive
    if (t == 1023) bsum[blockIdx.x] = s[t];    // block total
}

__global__ void k_scan_top(int* __restrict__ bsum, int* __restrict__ offsets, int nb, int n) {
    int t = threadIdx.x;  // 64 threads
    int v = (t < nb) ? bsum[t] : 0;
    int orig = v;
    for (int off = 1; off < 64; off <<= 1) {
        int u = __shfl_up(v, off, 64);
        if (t >= off) v += u;
    }
    if (t < nb) bsum[t] = v - orig;            // exclusive block offsets
    if (t == nb - 1) offsets[n] = v;           // grand total = E
}

__global__ void k_scan_add(int* __restrict__ offsets, int* __restrict__ cursor,
                           const int* __restrict__ bsum, int n) {
    int i = blockIdx.x * 1024 + threadIdx.x;
    if (i < n) {
        int o = offsets[i] + bsum[blockIdx.x];
        offsets[i] = o;
        cursor[i] = o;
    }
}

__global__ void k_scatter(const int* __restrict__ row, const int* __restrict__ col,
                          const float* __restrict__ ew, int* __restrict__ cursor,
                          uint2* __restrict__ packed, int E) {
    int e = blockIdx.x * blockDim.x + threadIdx.x;
    if (e < E) {
        int r = row[e];
        int pos = atomicAdd(&cursor[r], 1);
        packed[pos] = make_uint2((unsigned)col[e], __float_as_uint(ew[e]));
    }
}

// ---------------- weight transpose + fp16 convert: wt[n][k] = w[k][n] ----------------

__global__ void k_wt(const float* __restrict__ w, _Float16* __restrict__ wt) {
    __shared__ _Float16 tile[32][33];
    int bx = blockIdx.x & 15, by = blockIdx.x >> 4;
    int tx = threadIdx.x & 31, ty = threadIdx.x >> 5;  // 32 x 8
    for (int r = 0; r < 32; r += 8)
        tile[ty + r][tx] = (_Float16)w[(size_t)(by * 32 + ty + r) * 512 + bx * 32 + tx];
    __syncthreads();
    for (int r = 0; r < 32; r += 8)
        wt[(size_t)(bx * 32 + ty + r) * 512 + by * 32 + tx] = tile[tx][ty + r];
}

// ---------------- GEMM: sup[m][n] (fp16) = X[m][k] * W[k][n] ----------------

__launch_bounds__(256)
__global__ void k_gemm(const float* __restrict__ x, const _Float16* __restrict__ wt,
                       _Float16* __restrict__ sup, int M) {
    __shared__ __align__(16) unsigned char As[BM * BK * 2];  // 16 KB
    __shared__ __align__(16) unsigned char Bs[BN * BK * 2];  // 16 KB

    const int t = threadIdx.x;
    const int lane = t & 63, w = t >> 6;
    const int wr = w >> 1, wc = w & 1;
    const int m0 = blockIdx.x * BM, n0 = blockIdx.y * BN;

    f32x4 acc[4][4] = {};

    const int ar_t = t >> 4;            // row-in-group 0..15
    const int ac_t = (t & 15) * 4;      // f32 col 0,4,..,60
    const int bn_t = t >> 3;            // n within 32-group
    const int bk_sw = ((t & 7) * 16) ^ (((t >> 3) & 7) << 4);  // pre-swizzled src byte off

    for (int kt = 0; kt < D_DIM / BK; ++kt) {
        const int k0 = kt * BK;
        // B: 4x global_load_lds, 16B each, linear LDS dest, swizzled global src
        for (int j = 0; j < 4; ++j) {
            int n = j * 32 + bn_t;
            const char* src = (const char*)(wt + (size_t)(n0 + n) * 512 + k0) + bk_sw;
            __builtin_amdgcn_global_load_lds(GLB_PTR(src), LDS_PTR(Bs + j * 4096 + t * 16),
                                             16, 0, 0);
        }
        // A: reg-staged, 8 issues of float4 -> f16x4, swizzled ds_write
        for (int i = 0; i < 8; ++i) {
            int r = i * 16 + ar_t;
            int g = m0 + r;
            if (g >= M) g = M - 1;
            const float4 v = *(const float4*)(x + (size_t)g * 512 + k0 + ac_t);
            h4 hv;
            hv[0] = (_Float16)v.x; hv[1] = (_Float16)v.y;
            hv[2] = (_Float16)v.z; hv[3] = (_Float16)v.w;
            int addr = r * 128 + ((ac_t * 2) ^ ((r & 7) << 4));
            *(h4*)(As + addr) = hv;
        }
        __syncthreads();

        for (int ks = 0; ks < 2; ++ks) {
            h8 af[4], bf[4];
            const int kb = ks * 64 + ((lane >> 4) * 8) * 2;
#pragma unroll
            for (int mb = 0; mb < 4; ++mb) {
                int r = wr * 64 + mb * 16 + (lane & 15);
                af[mb] = *(const h8*)(As + r * 128 + (kb ^ ((r & 7) << 4)));
            }
#pragma unroll
            for (int nb = 0; nb < 4; ++nb) {
                int n = wc * 64 + nb * 16 + (lane & 15);
                bf[nb] = *(const h8*)(Bs + n * 128 + (kb ^ ((n & 7) << 4)));
            }
#pragma unroll
            for (int mb = 0; mb < 4; ++mb)
#pragma unroll
                for (int nb = 0; nb < 4; ++nb)
                    acc[mb][nb] = __builtin_amdgcn_mfma_f32_16x16x32_f16(
                        af[mb], bf[nb], acc[mb][nb], 0, 0, 0);
        }
        __syncthreads();
    }

    const int cr = (lane >> 4) * 4, cc = lane & 15;
#pragma unroll
    for (int mb = 0; mb < 4; ++mb) {
#pragma unroll
        for (int nb = 0; nb < 4; ++nb) {
            int gn = n0 + wc * 64 + nb * 16 + cc;
#pragma unroll
            for (int q = 0; q < 4; ++q) {
                int gm = m0 + wr * 64 + mb * 16 + cr + q;
                if (gm < M)
                    sup[(size_t)gm * 512 + gn] = (_Float16)acc[mb][nb][q];
            }
        }
    }
}

// ---------------- SpMM: one wave per output row, 4 rows/block, 8-deep ILP ----------------

__global__ void k_spmm(const _Float16* __restrict__ sup, const uint2* __restrict__ packed,
                       const int* __restrict__ offsets, const float* __restrict__ bias,
                       float* __restrict__ out, int M) {
    const int i = blockIdx.x * 4 + (threadIdx.x >> 6);
    if (i >= M) return;
    const int l = threadIdx.x & 63;
    const int s0 = offsets[i], s1 = offsets[i + 1];
    const _Float16* __restrict__ supl = sup + l * 8;

    float acc[8];
    {
        const float4 b0 = *(const float4*)(bias + l * 8);
        const float4 b1 = *(const float4*)(bias + l * 8 + 4);
        acc[0] = b0.x; acc[1] = b0.y; acc[2] = b0.z; acc[3] = b0.w;
        acc[4] = b1.x; acc[5] = b1.y; acc[6] = b1.z; acc[7] = b1.w;
    }

    int e = s0;
    // peel to even e so uint4 loads are 16B-aligned
    if ((e & 1) && e < s1) {
        uint2 p = packed[e];
        float wgt = __uint_as_float(p.y);
        h8 h = *(const h8*)(supl + (size_t)p.x * 512);
#pragma unroll
        for (int j = 0; j < 8; ++j) acc[j] += wgt * (float)h[j];
        ++e;
    }
    // main loop: 8 independent gathers in flight
    for (; e + 8 <= s1; e += 8) {
        const uint4 q0 = *(const uint4*)(packed + e);
        const uint4 q1 = *(const uint4*)(packed + e + 2);
        const uint4 q2 = *(const uint4*)(packed + e + 4);
        const uint4 q3 = *(const uint4*)(packed + e + 6);
        const h8 h0 = *(const h8*)(supl + (size_t)q0.x * 512);
        const h8 h1 = *(const h8*)(supl + (size_t)q0.z * 512);
        const h8 h2 = *(const h8*)(supl + (size_t)q1.x * 512);
        const h8 h3 = *(const h8*)(supl + (size_t)q1.z * 512);
        const h8 h4v = *(const h8*)(supl + (size_t)q2.x * 512);
        const h8 h5 = *(const h8*)(supl + (size_t)q2.z * 512);
        const h8 h6 = *(const h8*)(supl + (size_t)q3.x * 512);
        const h8 h7 = *(const h8*)(supl + (size_t)q3.z * 512);
        const float w0 = __uint_as_float(q0.y), w1 = __uint_as_float(q0.w);
        const float w2 = __uint_as_float(q1.y), w3 = __uint_as_float(q1.w);
        const float w4 = __uint_as_float(q2.y), w5 = __uint_as_float(q2.w);
        const float w6 = __uint_as_float(q3.y), w7 = __uint_as_float(q3.w);
#pragma unroll
        for (int j = 0; j < 8; ++j) {
            float a = acc[j];
            a += w0 * (float)h0[j];
            a += w1 * (float)h1[j];
            a += w2 * (float)h2[j];
            a += w3 * (float)h3[j];
            a += w4 * (float)h4v[j];
            a += w5 * (float)h5[j];
            a += w6 * (float)h6[j];
            a += w7 * (float)h7[j];
            acc[j] = a;
        }
    }
    // tail
    for (; e < s1; ++e) {
        uint2 p = packed[e];
        float wgt = __uint_as_float(p.y);
        h8 h = *(const h8*)(supl + (size_t)p.x * 512);
#pragma unroll
        for (int j = 0; j < 8; ++j) acc[j] += wgt * (float)h[j];
    }

    float4 o0 = {acc[0], acc[1], acc[2], acc[3]};
    float4 o1 = {acc[4], acc[5], acc[6], acc[7]};
    *(float4*)(out + (size_t)i * 512 + l * 8) = o0;
    *(float4*)(out + (size_t)i * 512 + l * 8 + 4) = o1;
}

// ---------------- launch ----------------

extern "C" void kernel_launch(void* const* d_in, const int* in_sizes, int n_in,
                              void* d_out, int out_size, void* d_ws, size_t ws_size,
                              hipStream_t stream) {
    const float* x      = (const float*)d_in[0];
    const float* weight = (const float*)d_in[1];
    const float* bias   = (const float*)d_in[2];
    const int*   row    = (const int*)d_in[3];
    const int*   col    = (const int*)d_in[4];
    const float* ew     = (const float*)d_in[5];
    const int M = in_sizes[0] / D_DIM;   // 50000
    const int E = in_sizes[3];           // 1600000
    float* out = (float*)d_out;

    char* ws = (char*)d_ws;
    size_t off = 0;
    auto alloc = [&](size_t bytes) {
        void* p = ws + off;
        off = (off + bytes + 255) & ~(size_t)255;
        return p;
    };
    _Float16* sup  = (_Float16*)alloc((size_t)M * D_DIM * 2);
    _Float16* wt   = (_Float16*)alloc((size_t)512 * 512 * 2);
    int* counts    = (int*)alloc((size_t)M * 4);
    int* offsets   = (int*)alloc((size_t)(M + 1) * 4);
    int* cursor    = (int*)alloc((size_t)M * 4);
    int* bsum      = (int*)alloc(64 * 4);
    uint2* packed  = (uint2*)alloc((size_t)E * 8);
    (void)ws_size; (void)n_in; (void)out_size;

    // CSR build
    k_zero<<<(M + 255) / 256, 256, 0, stream>>>(counts, M);
    k_count<<<(E + 255) / 256, 256, 0, stream>>>(row, counts, E);
    const int SB = (M + 1023) / 1024;  // 49
    k_scan_part<<<SB, 1024, 0, stream>>>(counts, offsets, bsum, M);
    k_scan_top<<<1, 64, 0, stream>>>(bsum, offsets, SB, M);
    k_scan_add<<<SB, 1024, 0, stream>>>(offsets, cursor, bsum, M);
    k_scatter<<<(E + 255) / 256, 256, 0, stream>>>(row, col, ew, cursor, packed, E);

    // dense path
    k_wt<<<256, 256, 0, stream>>>(weight, wt);
    dim3 gg((M + BM - 1) / BM, D_DIM / BN);
    k_gemm<<<gg, 256, 0, stream>>>(x, wt, sup, M);

    // gather-accumulate
    k_spmm<<<(M + 3) / 4, 256, 0, stream>>>(sup, packed, offsets, bias, out, M);
}